// Round 4
// baseline (480.432 us; speedup 1.0000x reference)
//
#include <hip/hip_runtime.h>

#define HDIM 768
#define BM 128               // rows per block: 4 pairs x 32
#define NCT 48               // col-tiles of 16
#define BSTRIDE 1600         // bytes per col in LDS B tile (1536 data + 64 pad)
#define BTILE (16 * BSTRIDE) // 25600 per buffer
#define NSTAGE 25            // 1024B staging instrs per tile

typedef _Float16 f16x8 __attribute__((ext_vector_type(8)));
typedef float f32x4 __attribute__((ext_vector_type(4)));

// ---- workspace layout (bytes) ----
#define WS_W16   0            // 768*768*2 = 1179648
#define WS_Z     1179648      // 4
#define WS_PART  1179712      // 1024*768*4 = 3145728
#define WS_PART2 4325440      // 8*768*4

// ---- LDS layout (bytes) ----
// 0     : B buf0 (25600) | buf1 (25600)        [tail: wstage 4x768 f32 reuses 0..12288]
// 51200 : zbuf 4 pair x 2 slot x 64 lane x 16B = 8192
// 59392 : bias fp16 (1536)
// 60928 : v fp16 (1536)
// 62464 : e_lds 128 f32 (512)
// 62976 : zred 8 f32 (32)   -> total 63008 (< 64KB, 2 blocks/CU)
#define LDS_ZBUF  51200
#define LDS_BIAS  59392
#define LDS_V     60928
#define LDS_E     62464
#define LDS_ZRED  62976
#define LDS_TOTAL 63008

__device__ __forceinline__ float tanh_fast(float z) {
    float e2 = __expf(2.0f * z);
    return 1.0f - 2.0f / (e2 + 1.0f);
}

__device__ __forceinline__ void stage16(const void* g, void* l) {
    __builtin_amdgcn_global_load_lds(
        (const __attribute__((address_space(1))) void*)g,
        (__attribute__((address_space(3))) void*)l, 16, 0, 0);
}

// ---------------- kernel 1: convert W to fp16, zero Z ----------------
__global__ __launch_bounds__(1024) void prep_kernel(
    const float* __restrict__ W, _Float16* __restrict__ W16, float* __restrict__ Z) {
    int idx = blockIdx.x * 1024 + threadIdx.x;
    if (idx < HDIM * HDIM) W16[idx] = (_Float16)W[idx];
    if (idx == 0) *Z = 0.0f;
}

// ---------------- kernel 2: fused GEMM + tanh + v-dot + exp + weighted sum ----------------
// 512 threads = 8 waves = 4 pairs; 32 rows/pair, K split 2x384 across the pair.
// A K-half in VGPRs (96), B double-buffered in LDS, z-halves exchanged via LDS zbuf.
__global__ __attribute__((amdgpu_waves_per_eu(4, 4)))
__launch_bounds__(512) void score_fused_kernel(
    const float* __restrict__ h, const _Float16* __restrict__ W16,
    const float* __restrict__ bias, const float* __restrict__ vvec,
    float* __restrict__ part, float* __restrict__ Z) {

    extern __shared__ char smem[];
    char*      zbufc   = smem + LDS_ZBUF;
    _Float16*  bias_s  = (_Float16*)(smem + LDS_BIAS);
    _Float16*  v_s     = (_Float16*)(smem + LDS_V);
    float*     e_lds   = (float*)(smem + LDS_E);
    float*     zred    = (float*)(smem + LDS_ZRED);
    float*     wstage  = (float*)smem;            // tail reuse: 4 x 768 f32

    const int tid  = threadIdx.x;
    const int wave = tid >> 6;       // 0..7
    const int lane = tid & 63;
    const int pair = wave >> 1;      // 0..3
    const int kh   = wave & 1;       // K-half: 0 -> k[0,384), 1 -> k[384,768)
    const int l15  = lane & 15;
    const int lhi  = lane >> 4;
    const int row0 = blockIdx.x * BM + pair * 32;

    // stage bias / v into LDS as fp16
    for (int j = tid; j < HDIM; j += 512) {
        bias_s[j] = (_Float16)bias[j];
        v_s[j]    = (_Float16)vvec[j];
    }

    // per-lane staging offsets: LDS-linear o -> (col c, byte b) -> W16 byte offset
    int soff[4];
    #pragma unroll
    for (int s = 0; s < 4; ++s) {
        int i = wave + 8 * s;
        int o = i * 1024 + lane * 16;
        int c = o / BSTRIDE;
        int b = o - c * BSTRIDE;
        if (b > 1520) b = 1520;      // pad region (never read): clamp in-bounds
        soff[s] = c * 1536 + b;
    }

    // stage col-tile 0 into buf0
    {
        const char* g = (const char*)W16;
        #pragma unroll
        for (int s = 0; s < 4; ++s)
            if (wave + 8 * s < NSTAGE)
                stage16(g + soff[s], smem + (wave + 8 * s) * 1024);
    }

    // ---- load A: 32 rows x 384 K-half as fp16 fragments (96 VGPRs) ----
    f16x8 a[2][12];
    const float* hb = h + (size_t)row0 * HDIM + kh * 384;
    #pragma unroll
    for (int rt = 0; rt < 2; ++rt) {
        const float* hr = hb + (size_t)(rt * 16 + l15) * HDIM + lhi * 8;
        #pragma unroll
        for (int kt = 0; kt < 12; ++kt) {
            f32x4 x0 = *(const f32x4*)(hr + kt * 32);
            f32x4 x1 = *(const f32x4*)(hr + kt * 32 + 4);
            f16x8 f;
            f[0] = (_Float16)x0[0]; f[1] = (_Float16)x0[1];
            f[2] = (_Float16)x0[2]; f[3] = (_Float16)x0[3];
            f[4] = (_Float16)x1[0]; f[5] = (_Float16)x1[1];
            f[6] = (_Float16)x1[2]; f[7] = (_Float16)x1[3];
            a[rt][kt] = f;
        }
    }

    __syncthreads();   // stage(0) + A-loads + bias/v staging complete

    float p[4] = {0.f, 0.f, 0.f, 0.f};

    for (int ct = 0; ct < NCT; ++ct) {
        const int buf = ct & 1;
        // issue staging of next tile into the other buffer
        if (ct + 1 < NCT) {
            const char* g = (const char*)W16 + (ct + 1) * 24576;
            char* ldsb = smem + (buf ^ 1) * BTILE;
            #pragma unroll
            for (int s = 0; s < 4; ++s)
                if (wave + 8 * s < NSTAGE)
                    stage16(g + soff[s], ldsb + (wave + 8 * s) * 1024);
        }
        // compute this wave's K-half: 12 k-steps, B-frag shared across 2 row-tiles
        const char* bbase = smem + buf * BTILE + l15 * BSTRIDE + kh * 768 + lhi * 16;
        f32x4 acc0 = {0.f, 0.f, 0.f, 0.f};
        f32x4 acc1 = {0.f, 0.f, 0.f, 0.f};
        #pragma unroll
        for (int kt = 0; kt < 12; ++kt) {
            f16x8 bfr = *(const f16x8*)(bbase + kt * 64);
            acc0 = __builtin_amdgcn_mfma_f32_16x16x32_f16(a[0][kt], bfr, acc0, 0, 0, 0);
            acc1 = __builtin_amdgcn_mfma_f32_16x16x32_f16(a[1][kt], bfr, acc1, 0, 0, 0);
        }
        // exchange: I finalize row-tile rt==kh; send acc_{1-kh}, receive partner's acc_{kh}
        f32x4 accsend = kh ? acc0 : acc1;
        f32x4 acckeep = kh ? acc1 : acc0;
        *(f32x4*)(zbufc + (((pair * 2) + (1 - kh)) * 64 + lane) * 16) = accsend;
        __syncthreads();   // zbuf visible; stage of ct+1 drained (vmcnt 0)
        f32x4 zp = *(const f32x4*)(zbufc + (((pair * 2) + kh) * 64 + lane) * 16);
        float bj = (float)bias_s[ct * 16 + l15];
        float vj = (float)v_s[ct * 16 + l15];
        #pragma unroll
        for (int r = 0; r < 4; ++r) {
            float t = tanh_fast(acckeep[r] + zp[r] + bj);
            p[r] = fmaf(vj, t, p[r]);
        }
        __syncthreads();   // everyone done reading zbuf before next tile overwrites it
    }

    // ---- scores: reduce p over the 16 l15 lanes (cols) ----
    #pragma unroll
    for (int m = 1; m <= 8; m <<= 1) {
        p[0] += __shfl_xor(p[0], m);
        p[1] += __shfl_xor(p[1], m);
        p[2] += __shfl_xor(p[2], m);
        p[3] += __shfl_xor(p[3], m);
    }
    // e = exp(s); this wave owns rows pair*32 + kh*16 + lhi*4 + r
    float ev[4];
    float zsum = 0.f;
    #pragma unroll
    for (int r = 0; r < 4; ++r) {
        ev[r] = __expf(p[r]);
        zsum += ev[r];
    }
    zsum += __shfl_xor(zsum, 16);
    zsum += __shfl_xor(zsum, 32);
    if (lane == 0) zred[wave] = zsum;
    if (l15 == 0) {
        #pragma unroll
        for (int r = 0; r < 4; ++r)
            e_lds[pair * 32 + kh * 16 + lhi * 4 + r] = ev[r];
    }
    __syncthreads();

    // ---- fused weighted sum over this wave's 32 rows x its K-half j-range ----
    float er0 = e_lds[pair * 32 + l15];        // rows rt=0 (matches a[0] row = l15)
    float er1 = e_lds[pair * 32 + 16 + l15];   // rows rt=1
    #pragma unroll
    for (int kt = 0; kt < 12; ++kt) {
        float w[8];
        #pragma unroll
        for (int e2 = 0; e2 < 8; ++e2)
            w[e2] = er0 * (float)a[0][kt][e2] + er1 * (float)a[1][kt][e2];
        #pragma unroll
        for (int e2 = 0; e2 < 8; ++e2) {
            #pragma unroll
            for (int m = 1; m <= 8; m <<= 1) w[e2] += __shfl_xor(w[e2], m);
        }
        if (l15 == 0) {   // j = kh*384 + kt*32 + lhi*8 + e2 ; disjoint across kh
            f32x4 w0 = {w[0], w[1], w[2], w[3]};
            f32x4 w1 = {w[4], w[5], w[6], w[7]};
            float* dst = wstage + pair * HDIM + kh * 384 + kt * 32 + lhi * 8;
            *(f32x4*)dst       = w0;
            *(f32x4*)(dst + 4) = w1;
        }
    }
    __syncthreads();

    // cross-pair partial + block Z
    for (int j = tid; j < HDIM; j += 512) {
        float s = wstage[j] + wstage[HDIM + j] + wstage[2 * HDIM + j] + wstage[3 * HDIM + j];
        part[(size_t)blockIdx.x * HDIM + j] = s;
    }
    if (tid == 0)
        atomicAdd(Z, zred[0] + zred[1] + zred[2] + zred[3] +
                     zred[4] + zred[5] + zred[6] + zred[7]);
}

// ---------------- finalize stage 1: sum 1024 parts in groups of 128 ----------------
__global__ __launch_bounds__(128) void fin1_kernel(
    const float* __restrict__ part, float* __restrict__ part2) {
    const int g  = blockIdx.x / 6;           // part-group 0..7
    const int cb = blockIdx.x % 6;
    const int col = cb * 128 + threadIdx.x;
    float s = 0.f;
    #pragma unroll 8
    for (int p = g * 128; p < (g + 1) * 128; ++p) s += part[(size_t)p * HDIM + col];
    part2[g * HDIM + col] = s;
}

// ---------------- finalize stage 2: out[j] = sum_g part2[g][j] / Z ----------------
__global__ __launch_bounds__(128) void fin2_kernel(
    const float* __restrict__ part2, const float* __restrict__ Z,
    float* __restrict__ out) {
    const int col = blockIdx.x * 128 + threadIdx.x;
    float s = 0.f;
    #pragma unroll
    for (int g = 0; g < 8; ++g) s += part2[g * HDIM + col];
    out[col] = s / (*Z);
}

extern "C" void kernel_launch(void* const* d_in, const int* in_sizes, int n_in,
                              void* d_out, int out_size, void* d_ws, size_t ws_size,
                              hipStream_t stream) {
    const float* h    = (const float*)d_in[0];   // [N, 768]
    const float* W    = (const float*)d_in[1];   // [768, 768]
    const float* bias = (const float*)d_in[2];   // [768]
    const float* vv   = (const float*)d_in[3];   // [1, 768]
    float* out = (float*)d_out;                  // [1, 768] fp32

    const int n = in_sizes[0] / HDIM;            // 131072

    char* ws = (char*)d_ws;
    _Float16* W16 = (_Float16*)(ws + WS_W16);
    float* Z      = (float*)(ws + WS_Z);
    float* part   = (float*)(ws + WS_PART);
    float* part2  = (float*)(ws + WS_PART2);

    // 1) W -> fp16, zero Z
    prep_kernel<<<(HDIM * HDIM + 1023) / 1024, 1024, 0, stream>>>(W, W16, Z);

    // 2) fused score + exp + weighted-sum partials
    score_fused_kernel<<<n / BM, 512, LDS_TOTAL, stream>>>(h, W16, bias, vv, part, Z);

    // 3) reduce partials
    fin1_kernel<<<48, 128, 0, stream>>>(part, part2);
    fin2_kernel<<<HDIM / 128, 128, 0, stream>>>(part2, Z, out);
}

// Round 5
// 405.096 us; speedup vs baseline: 1.1860x; 1.1860x over previous
//
#include <hip/hip_runtime.h>

#define HDIM 768
#define BM 128              // rows per block (4 waves x 32)
#define NCT 48              // col-tiles of 16
#define BSTRIDE 1600        // bytes per col in LDS B tile (1536 data + 64 pad)
#define BTILE (16 * BSTRIDE)        // 25600 bytes per buffer
#define NSTAGE 25           // 1024B global_load_lds per tile

typedef _Float16 f16x8 __attribute__((ext_vector_type(8)));
typedef float f32x4 __attribute__((ext_vector_type(4)));

// ---- workspace layout (bytes) ----
#define WS_W16   0            // 768*768*2 = 1179648
#define WS_Z     1179648      // 4
#define WS_PART  1179712      // 1024*768*4 = 3145728
#define WS_PART2 4325440      // 8*768*4

__device__ __forceinline__ float tanh_fast(float z) {
    float e2 = __expf(2.0f * z);
    return 1.0f - 2.0f / (e2 + 1.0f);
}

__device__ __forceinline__ void stage16(const void* g, void* l) {
    __builtin_amdgcn_global_load_lds(
        (const __attribute__((address_space(1))) void*)g,
        (__attribute__((address_space(3))) void*)l, 16, 0, 0);
}

__device__ __forceinline__ f16x8 cvt8(f32x4 x0, f32x4 x1) {
    f16x8 f;
    f[0] = (_Float16)x0[0]; f[1] = (_Float16)x0[1];
    f[2] = (_Float16)x0[2]; f[3] = (_Float16)x0[3];
    f[4] = (_Float16)x1[0]; f[5] = (_Float16)x1[1];
    f[6] = (_Float16)x1[2]; f[7] = (_Float16)x1[3];
    return f;
}

// X-macro over the 24 k-steps
#define KT_ITER(X) X(0) X(1) X(2) X(3) X(4) X(5) X(6) X(7) X(8) X(9) X(10) X(11) \
                   X(12) X(13) X(14) X(15) X(16) X(17) X(18) X(19) X(20) X(21) X(22) X(23)

// ---------------- kernel 1: convert W to fp16, zero Z ----------------
__global__ __launch_bounds__(1024) void prep_kernel(
    const float* __restrict__ W, _Float16* __restrict__ W16, float* __restrict__ Z) {
    int idx = blockIdx.x * 1024 + threadIdx.x;
    if (idx < HDIM * HDIM) W16[idx] = (_Float16)W[idx];
    if (idx == 0) *Z = 0.0f;
}

// ---------------- kernel 2: fused GEMM + tanh + v-dot + exp + weighted sum ----------------
// 256 threads (4 waves), 128 rows/block, grid 1024. A tile lives in 48 NAMED f16x8
// locals (192 VGPRs, no alloca -> no promote-alloca failure). Static __shared__ so the
// allocator sees LDS-capped residency (2 blocks/CU) and grants the 256-VGPR budget.
// Rounds 2-4: extern-shared + a[][] array => whole tile in scratch (WRITE_SIZE 300-490MB).
struct SMem {
    char  bbuf[2][BTILE];   // 51200: B double buffer
    float bias_s[HDIM];     // 3072
    float v_s[HDIM];        // 3072
    float e_lds[128];       // 512
    float zred[4];          // 16   -> 57872 B total (static)
};

__global__ __launch_bounds__(256, 2) void score_fused_kernel(
    const float* __restrict__ h, const _Float16* __restrict__ W16,
    const float* __restrict__ bias, const float* __restrict__ vvec,
    float* __restrict__ part, float* __restrict__ Z) {

    __shared__ SMem sm;
    char*  smem   = (char*)&sm;
    float* wstage = (float*)&sm;    // tail reuse of bbuf area: 4 x 768 f32

    const int tid  = threadIdx.x;
    const int wave = tid >> 6;
    const int lane = tid & 63;
    const int l15  = lane & 15;
    const int lhi  = lane >> 4;
    const int row0 = blockIdx.x * BM + wave * 32;

    // stage bias / v into LDS
    for (int j = tid; j < HDIM; j += 256) { sm.bias_s[j] = bias[j]; sm.v_s[j] = vvec[j]; }

    // per-lane staging source offsets: LDS-linear o -> (col c, byte b) -> W16 byte offset
    int soff[7];
    #pragma unroll
    for (int s = 0; s < 7; ++s) {
        int i = wave + 4 * s;
        int o = i * 1024 + lane * 16;
        int c = o / BSTRIDE;
        int b = o - c * BSTRIDE;
        if (b > 1520) b = 1520;          // pad region (never read): clamp in-bounds
        soff[s] = c * 1536 + b;
    }

    // stage col-tile 0 into buf0
    {
        const char* g = (const char*)W16;
        #pragma unroll
        for (int s = 0; s < 7; ++s)
            if (wave + 4 * s < NSTAGE)
                stage16(g + soff[s], smem + (wave + 4 * s) * 1024);
    }

    // ---- load A: 32 rows x 768 K as 48 named f16x8 fragments ----
    const float* hr0 = h + (size_t)(row0 + l15) * HDIM + lhi * 8;        // rows 0..15
    const float* hr1 = h + (size_t)(row0 + 16 + l15) * HDIM + lhi * 8;   // rows 16..31

#define DECL_A(k) f16x8 A0_##k, A1_##k;
    KT_ITER(DECL_A)
#undef DECL_A

#define LOAD_A(k) { \
        f32x4 x0 = *(const f32x4*)(hr0 + (k) * 32); \
        f32x4 x1 = *(const f32x4*)(hr0 + (k) * 32 + 4); \
        A0_##k = cvt8(x0, x1); \
        f32x4 y0 = *(const f32x4*)(hr1 + (k) * 32); \
        f32x4 y1 = *(const f32x4*)(hr1 + (k) * 32 + 4); \
        A1_##k = cvt8(y0, y1); }
    KT_ITER(LOAD_A)
#undef LOAD_A

    __syncthreads();   // stage(0) + A-loads + bias/v staging complete

    float p0[4] = {0.f, 0.f, 0.f, 0.f};
    float p1[4] = {0.f, 0.f, 0.f, 0.f};

    for (int ct = 0; ct < NCT; ++ct) {
        const int buf = ct & 1;
        // issue staging of next tile into the other buffer
        if (ct + 1 < NCT) {
            const char* g = (const char*)W16 + (ct + 1) * 24576;
            char* ldsb = smem + (buf ^ 1) * BTILE;
            #pragma unroll
            for (int s = 0; s < 7; ++s)
                if (wave + 4 * s < NSTAGE)
                    stage16(g + soff[s], ldsb + (wave + 4 * s) * 1024);
        }
        // compute current tile: 24 k-steps, B-frag shared across 2 row-tiles
        const char* bbase = smem + buf * BTILE + l15 * BSTRIDE + lhi * 16;
        f32x4 acc0 = {0.f, 0.f, 0.f, 0.f};
        f32x4 acc1 = {0.f, 0.f, 0.f, 0.f};
#define MFMA_STEP(k) { \
            f16x8 bfr = *(const f16x8*)(bbase + (k) * 64); \
            acc0 = __builtin_amdgcn_mfma_f32_16x16x32_f16(A0_##k, bfr, acc0, 0, 0, 0); \
            acc1 = __builtin_amdgcn_mfma_f32_16x16x32_f16(A1_##k, bfr, acc1, 0, 0, 0); }
        KT_ITER(MFMA_STEP)
#undef MFMA_STEP

        // epilogue: p += v_j * tanh(z + b_j) for this tile's 16 cols (col = ct*16 + l15)
        float bj = sm.bias_s[ct * 16 + l15];
        float vj = sm.v_s[ct * 16 + l15];
        #pragma unroll
        for (int r = 0; r < 4; ++r) {
            p0[r] = fmaf(vj, tanh_fast(acc0[r] + bj), p0[r]);
            p1[r] = fmaf(vj, tanh_fast(acc1[r] + bj), p1[r]);
        }
        __syncthreads();   // next buffer fully staged (vmcnt drained), all waves done reading
    }

    // ---- scores: reduce p over the 16 l15 lanes (cols) ----
    #pragma unroll
    for (int r = 0; r < 4; ++r) {
        #pragma unroll
        for (int m = 1; m <= 8; m <<= 1) {
            p0[r] += __shfl_xor(p0[r], m);
            p1[r] += __shfl_xor(p1[r], m);
        }
    }
    // e = exp(s); rows held: rt*16 + lhi*4 + r (duplicated across 16 l15 lanes)
    float e0[4], e1[4];
    float zsum = 0.f;
    #pragma unroll
    for (int r = 0; r < 4; ++r) {
        e0[r] = __expf(p0[r]);
        e1[r] = __expf(p1[r]);
        zsum += e0[r] + e1[r];
    }
    zsum += __shfl_xor(zsum, 16);
    zsum += __shfl_xor(zsum, 32);
    if (lane == 0) sm.zred[wave] = zsum;
    if (l15 == 0) {
        #pragma unroll
        for (int r = 0; r < 4; ++r) {
            sm.e_lds[wave * 32 + lhi * 4 + r]      = e0[r];
            sm.e_lds[wave * 32 + 16 + lhi * 4 + r] = e1[r];
        }
    }
    __syncthreads();

    // ---- fused weighted sum: wstage[wave][j] = sum over wave's 32 rows of e_i * h_ij ----
    float er0 = sm.e_lds[wave * 32 + l15];        // row l15      (matches A0 row)
    float er1 = sm.e_lds[wave * 32 + 16 + l15];   // row 16 + l15 (matches A1 row)
#define WSUM(k) { \
        float w[8]; \
        _Pragma("unroll") \
        for (int e2 = 0; e2 < 8; ++e2) \
            w[e2] = er0 * (float)A0_##k[e2] + er1 * (float)A1_##k[e2]; \
        _Pragma("unroll") \
        for (int e2 = 0; e2 < 8; ++e2) { \
            w[e2] += __shfl_xor(w[e2], 1); \
            w[e2] += __shfl_xor(w[e2], 2); \
            w[e2] += __shfl_xor(w[e2], 4); \
            w[e2] += __shfl_xor(w[e2], 8); \
        } \
        if (l15 == 0) { \
            f32x4 w0v = {w[0], w[1], w[2], w[3]}; \
            f32x4 w1v = {w[4], w[5], w[6], w[7]}; \
            float* dst = wstage + wave * HDIM + (k) * 32 + lhi * 8; \
            *(f32x4*)dst       = w0v; \
            *(f32x4*)(dst + 4) = w1v; } }
    KT_ITER(WSUM)
#undef WSUM
    __syncthreads();

    // cross-wave partial + block Z
    for (int j = tid; j < HDIM; j += 256) {
        float s = wstage[j] + wstage[HDIM + j] + wstage[2 * HDIM + j] + wstage[3 * HDIM + j];
        part[(size_t)blockIdx.x * HDIM + j] = s;
    }
    if (tid == 0) atomicAdd(Z, sm.zred[0] + sm.zred[1] + sm.zred[2] + sm.zred[3]);
}

// ---------------- finalize stage 1: sum 1024 parts in groups of 128 ----------------
__global__ __launch_bounds__(128) void fin1_kernel(
    const float* __restrict__ part, float* __restrict__ part2) {
    const int g  = blockIdx.x / 6;           // part-group 0..7
    const int cb = blockIdx.x % 6;
    const int col = cb * 128 + threadIdx.x;
    float s = 0.f;
    #pragma unroll 8
    for (int p = g * 128; p < (g + 1) * 128; ++p) s += part[(size_t)p * HDIM + col];
    part2[g * HDIM + col] = s;
}

// ---------------- finalize stage 2: out[j] = sum_g part2[g][j] / Z ----------------
__global__ __launch_bounds__(128) void fin2_kernel(
    const float* __restrict__ part2, const float* __restrict__ Z,
    float* __restrict__ out) {
    const int col = blockIdx.x * 128 + threadIdx.x;
    float s = 0.f;
    #pragma unroll
    for (int g = 0; g < 8; ++g) s += part2[g * HDIM + col];
    out[col] = s / (*Z);
}

extern "C" void kernel_launch(void* const* d_in, const int* in_sizes, int n_in,
                              void* d_out, int out_size, void* d_ws, size_t ws_size,
                              hipStream_t stream) {
    const float* h    = (const float*)d_in[0];   // [N, 768]
    const float* W    = (const float*)d_in[1];   // [768, 768]
    const float* bias = (const float*)d_in[2];   // [768]
    const float* vv   = (const float*)d_in[3];   // [1, 768]
    float* out = (float*)d_out;                  // [1, 768] fp32

    const int n = in_sizes[0] / HDIM;            // 131072

    char* ws = (char*)d_ws;
    _Float16* W16 = (_Float16*)(ws + WS_W16);
    float* Z      = (float*)(ws + WS_Z);
    float* part   = (float*)(ws + WS_PART);
    float* part2  = (float*)(ws + WS_PART2);

    // 1) W -> fp16, zero Z
    prep_kernel<<<(HDIM * HDIM + 1023) / 1024, 1024, 0, stream>>>(W, W16, Z);

    // 2) fused score + exp + weighted-sum partials (static LDS: no dynamic smem arg)
    score_fused_kernel<<<n / BM, 256, 0, stream>>>(h, W16, bias, vv, part, Z);

    // 3) reduce partials
    fin1_kernel<<<48, 128, 0, stream>>>(part, part2);
    fin2_kernel<<<HDIM / 128, 128, 0, stream>>>(part2, Z, out);
}

// Round 6
// 345.659 us; speedup vs baseline: 1.3899x; 1.1720x over previous
//
#include <hip/hip_runtime.h>

#define HDIM 768
#define BM 64                 // rows per block
#define NCHUNK 24             // K chunks of 32
#define CHUNK_BYTES 49152     // 768 cols * 32 k * 2B per chunk of Wt
#define A_STRIDE 1552         // bytes per A row in LDS (768 halves + 8 pad)

typedef _Float16 f16x8 __attribute__((ext_vector_type(8)));
typedef _Float16 f16x4 __attribute__((ext_vector_type(4)));
typedef float f32x4 __attribute__((ext_vector_type(4)));

// ---- LDS layout (bytes), dynamic, 151 KB ----
#define LDS_B     99328                  // A: [64][1552B] = 99328
#define LDS_BIAS  (LDS_B + CHUNK_BYTES)  // 148480: 768 f32
#define LDS_V     (LDS_BIAS + 3072)      // 151552: 768 f32
#define LDS_TOTAL (LDS_V + 3072)         // 154624
// post-K-loop overlays in the B region: s_red [16][64] f32 @ LDS_B, e_lds [64] f32 @ LDS_B+4096

// ---- workspace layout (bytes) ----
#define WS_WT    0                       // 768*768*2 = 1179648 (transposed fp16 W)
#define WS_Z     1179648                 // 4 (+pad)
#define WS_PART  1179712                 // 2048*768*4 = 6291456
#define WS_PART2 7471168                 // 16*768*4 = 49152
#define WS_NEED  (WS_PART2 + 49152)

__device__ __forceinline__ float tanh_fast(float z) {
    float e2 = __expf(2.0f * z);
    return 1.0f - 2.0f / (e2 + 1.0f);   // inf-safe at both extremes
}

__device__ __forceinline__ void stage16(const void* g, void* l) {
    __builtin_amdgcn_global_load_lds(
        (const __attribute__((address_space(1))) void*)g,
        (__attribute__((address_space(3))) void*)l, 16, 0, 0);
}

// ---------------- kernel 1: W -> fp16, transposed to [kc][col][32k]; zero Z + acc ----------------
__global__ __launch_bounds__(1024) void prep_kernel(
    const float* __restrict__ W, _Float16* __restrict__ Wt,
    float* __restrict__ Z, float* __restrict__ accbuf) {
    int idx = blockIdx.x * 1024 + threadIdx.x;      // over 147456 f32x4 groups
    if (idx < HDIM * HDIM / 4) {
        int j  = idx / 192;          // output col (row of W)
        int r  = idx - j * 192;
        int kc = r >> 3;
        int k4 = r & 7;
        f32x4 x = *(const f32x4*)(W + j * HDIM + kc * 32 + k4 * 4);
        f16x4 v;
        v[0] = (_Float16)x[0]; v[1] = (_Float16)x[1];
        v[2] = (_Float16)x[2]; v[3] = (_Float16)x[3];
        *(f16x4*)(Wt + kc * 24576 + j * 32 + k4 * 4) = v;
    }
    if (idx < HDIM) accbuf[idx] = 0.0f;
    if (idx == 0) *Z = 0.0f;
}

// ---------------- kernel 2: fused GEMM + tanh + v-dot + exp + weighted sum ----------------
// 1024 threads (16 waves), 64 rows/block, grid 2048, 1 block/CU (151KB LDS).
// A resident in LDS (staged incrementally per K-chunk); B single-buffered with
// register prefetch (T14). Wave = 4 row-tiles x 3 col-tiles; acc[4][3] = 48 VGPR.
__global__ __launch_bounds__(1024, 2) void score_fused_kernel(
    const float* __restrict__ h, const _Float16* __restrict__ Wt,
    const float* __restrict__ bias, const float* __restrict__ vvec,
    float* __restrict__ part, float* __restrict__ accbuf,
    float* __restrict__ Z, int use_part) {

    extern __shared__ char smem[];
    float* bias_s = (float*)(smem + LDS_BIAS);
    float* v_s    = (float*)(smem + LDS_V);
    float* s_red  = (float*)(smem + LDS_B);          // overlay, used after K-loop
    float* e_lds  = (float*)(smem + LDS_B + 4096);   // overlay

    const int tid  = threadIdx.x;
    const int wave = tid >> 6;       // 0..15
    const int lane = tid & 63;
    const int l15  = lane & 15;
    const int lhi  = lane >> 4;
    const int row0 = blockIdx.x * BM;

    // stage bias / v
    if (tid < HDIM) { bias_s[tid] = bias[tid]; v_s[tid] = vvec[tid]; }

    // prologue: B chunk 0 via global_load_lds (Wt chunk is contiguous -> linear copy)
    {
        const char* g = (const char*)Wt;
        #pragma unroll
        for (int s = 0; s < 3; ++s) {
            int idx = wave * 3 + s;
            stage16(g + idx * 1024 + lane * 16, smem + LDS_B + idx * 1024);
        }
    }
    // prologue: A chunk 0 (64 rows x 32 k, fp32 -> fp16)
    if (tid < 512) {
        int r = tid >> 3, k4 = tid & 7;
        f32x4 x = *(const f32x4*)(h + (size_t)(row0 + r) * HDIM + k4 * 4);
        f16x4 v;
        v[0] = (_Float16)x[0]; v[1] = (_Float16)x[1];
        v[2] = (_Float16)x[2]; v[3] = (_Float16)x[3];
        *(f16x4*)(smem + r * A_STRIDE + k4 * 8) = v;
    }
    __syncthreads();

    f32x4 acc[4][3];
    #pragma unroll
    for (int rt = 0; rt < 4; ++rt)
        #pragma unroll
        for (int ct = 0; ct < 3; ++ct)
            acc[rt][ct] = (f32x4){0.f, 0.f, 0.f, 0.f};

    const char* bbase0 = smem + LDS_B + (wave * 48 + l15) * 64 + lhi * 16;
    const char* abase0 = smem + l15 * A_STRIDE + lhi * 16;

    for (int kc = 0; kc < NCHUNK; ++kc) {
        // prefetch next chunk to registers (T14: issue early, write late)
        f32x4 pb0, pb1, pb2, pa;
        const bool has = (kc + 1 < NCHUNK);
        if (has) {
            const char* src = (const char*)Wt + (size_t)(kc + 1) * CHUNK_BYTES;
            pb0 = *(const f32x4*)(src + 0 * 16384 + tid * 16);
            pb1 = *(const f32x4*)(src + 1 * 16384 + tid * 16);
            pb2 = *(const f32x4*)(src + 2 * 16384 + tid * 16);
            if (tid < 512)
                pa = *(const f32x4*)(h + (size_t)(row0 + (tid >> 3)) * HDIM
                                       + (kc + 1) * 32 + (tid & 7) * 4);
        }
        // compute current chunk: 7 ds_read_b128 -> 12 MFMAs
        const char* bb = bbase0;
        f16x8 b0 = *(const f16x8*)(bb);
        f16x8 b1 = *(const f16x8*)(bb + 1024);
        f16x8 b2 = *(const f16x8*)(bb + 2048);
        const char* ab = abase0 + kc * 64;
        #pragma unroll
        for (int rt = 0; rt < 4; ++rt) {
            f16x8 av = *(const f16x8*)(ab + rt * (16 * A_STRIDE));
            acc[rt][0] = __builtin_amdgcn_mfma_f32_16x16x32_f16(av, b0, acc[rt][0], 0, 0, 0);
            acc[rt][1] = __builtin_amdgcn_mfma_f32_16x16x32_f16(av, b1, acc[rt][1], 0, 0, 0);
            acc[rt][2] = __builtin_amdgcn_mfma_f32_16x16x32_f16(av, b2, acc[rt][2], 0, 0, 0);
        }
        __syncthreads();   // all waves done reading B[kc] / A[kc]
        if (has) {
            *(f32x4*)(smem + LDS_B + 0 * 16384 + tid * 16) = pb0;
            *(f32x4*)(smem + LDS_B + 1 * 16384 + tid * 16) = pb1;
            *(f32x4*)(smem + LDS_B + 2 * 16384 + tid * 16) = pb2;
            if (tid < 512) {
                f16x4 v;
                v[0] = (_Float16)pa[0]; v[1] = (_Float16)pa[1];
                v[2] = (_Float16)pa[2]; v[3] = (_Float16)pa[3];
                *(f16x4*)(smem + (tid >> 3) * A_STRIDE + (kc + 1) * 64 + (tid & 7) * 8) = v;
            }
            __syncthreads();   // B[kc+1]/A[kc+1] visible
        }
    }

    // ---- epilogue: per-wave col-partial scores ----
    float pr[4][4];
    #pragma unroll
    for (int rt = 0; rt < 4; ++rt)
        #pragma unroll
        for (int r = 0; r < 4; ++r) pr[rt][r] = 0.f;

    #pragma unroll
    for (int ct = 0; ct < 3; ++ct) {
        int col = wave * 48 + ct * 16 + l15;
        float bj = bias_s[col];
        float vj = v_s[col];
        #pragma unroll
        for (int rt = 0; rt < 4; ++rt)
            #pragma unroll
            for (int r = 0; r < 4; ++r)
                pr[rt][r] = fmaf(vj, tanh_fast(acc[rt][ct][r] + bj), pr[rt][r]);
    }
    // reduce over the 16 l15 lanes (cols of this wave)
    #pragma unroll
    for (int rt = 0; rt < 4; ++rt)
        #pragma unroll
        for (int r = 0; r < 4; ++r) {
            float x = pr[rt][r];
            x += __shfl_xor(x, 1);
            x += __shfl_xor(x, 2);
            x += __shfl_xor(x, 4);
            x += __shfl_xor(x, 8);
            if (l15 == 0) s_red[wave * 64 + rt * 16 + lhi * 4 + r] = x;
        }
    __syncthreads();

    // rows: sum 16 wave-partials, exp, block Z
    if (tid < 64) {
        float s = 0.f;
        #pragma unroll
        for (int w = 0; w < 16; ++w) s += s_red[w * 64 + tid];
        float e = __expf(s);            // |s| <= ||v||_1 ~ 61: no overflow
        e_lds[tid] = e;
        float tot = e;
        tot += __shfl_xor(tot, 1);
        tot += __shfl_xor(tot, 2);
        tot += __shfl_xor(tot, 4);
        tot += __shfl_xor(tot, 8);
        tot += __shfl_xor(tot, 16);
        tot += __shfl_xor(tot, 32);
        if (tid == 0) atomicAdd(Z, tot);
    }
    __syncthreads();

    // ---- fused weighted sum: out_j partial = sum_i e_i * A_lds[i][j] ----
    if (tid < HDIM) {
        const _Float16* A = (const _Float16*)smem;
        float s = 0.f;
        #pragma unroll 8
        for (int i = 0; i < BM; ++i)
            s += e_lds[i] * (float)A[i * 776 + tid];
        if (use_part) part[(size_t)blockIdx.x * HDIM + tid] = s;
        else          atomicAdd(accbuf + tid, s);
    }
}

// ---------------- finalize stage 1 (big-ws path): sum 2048 parts in 16 groups of 128 ----------------
__global__ __launch_bounds__(128) void fin1_kernel(
    const float* __restrict__ part, float* __restrict__ part2) {
    const int g  = blockIdx.x / 6;           // group 0..15
    const int cb = blockIdx.x % 6;
    const int col = cb * 128 + threadIdx.x;
    float s = 0.f;
    #pragma unroll 8
    for (int p = g * 128; p < (g + 1) * 128; ++p) s += part[(size_t)p * HDIM + col];
    part2[g * HDIM + col] = s;
}

// ---------------- finalize stage 2: out[j] = sum_g src[g][j] / Z ----------------
__global__ __launch_bounds__(128) void fin2_kernel(
    const float* __restrict__ src, const float* __restrict__ Z,
    float* __restrict__ out, int ngroups) {
    const int col = blockIdx.x * 128 + threadIdx.x;
    float s = 0.f;
    for (int g = 0; g < ngroups; ++g) s += src[g * HDIM + col];
    out[col] = s / (*Z);
}

extern "C" void kernel_launch(void* const* d_in, const int* in_sizes, int n_in,
                              void* d_out, int out_size, void* d_ws, size_t ws_size,
                              hipStream_t stream) {
    const float* h    = (const float*)d_in[0];   // [N, 768]
    const float* W    = (const float*)d_in[1];   // [768, 768]
    const float* bias = (const float*)d_in[2];   // [768]
    const float* vv   = (const float*)d_in[3];   // [1, 768]
    float* out = (float*)d_out;                  // [1, 768] fp32

    const int n = in_sizes[0] / HDIM;            // 131072

    char* ws = (char*)d_ws;
    _Float16* Wt  = (_Float16*)(ws + WS_WT);
    float* Z      = (float*)(ws + WS_Z);
    float* part   = (float*)(ws + WS_PART);
    float* part2  = (float*)(ws + WS_PART2);
    float* accbuf = (float*)(ws + WS_PART);      // small-ws fallback accumulator

    const int use_part = (ws_size >= (size_t)WS_NEED) ? 1 : 0;

    // allow 151KB dynamic LDS for the fused kernel (host-side, capture-safe)
    hipFuncSetAttribute((const void*)score_fused_kernel,
                        hipFuncAttributeMaxDynamicSharedMemorySize, LDS_TOTAL);

    // 1) W -> fp16 transposed chunks; zero Z (+acc)
    prep_kernel<<<144, 1024, 0, stream>>>(W, Wt, Z, accbuf);

    // 2) fused score + exp + weighted-sum partials
    score_fused_kernel<<<n / BM, 1024, LDS_TOTAL, stream>>>(
        h, Wt, bias, vv, part, accbuf, Z, use_part);

    // 3) reduce partials
    if (use_part) {
        fin1_kernel<<<96, 128, 0, stream>>>(part, part2);
        fin2_kernel<<<HDIM / 128, 128, 0, stream>>>(part2, Z, out, 16);
    } else {
        fin2_kernel<<<HDIM / 128, 128, 0, stream>>>(accbuf, Z, out, 1);
    }
}